// Round 4
// baseline (1141.638 us; speedup 1.0000x reference)
//
#include <hip/hip_runtime.h>

// RPN anchor-target assignment. B=8, A=184320, G=64.
// Outputs (flat float32, concatenated): labels[B*A], matched[B*A*4], max_iou[B*A].
//
// Strategy: counting-sort anchors into 10px spatial cells so each wave's 64
// anchors are co-located; per wave, build a conservative 64-bit mask of gts
// whose box can overlap the wave bbox (expected ~6/64 survive), and run the
// exact IEEE IoU loop only over surviving gts. Skipped gts have iou==0 for
// every lane (mask is a superset of true overlaps), handled exactly by
// maxv init 0.0 and KEY_INIT column keys. Rule-1 fixup runs inline in the
// last finishing block (device-scope fence + done counter).

constexpr int B = 8;
constexpr int G = 64;
constexpr int BLOCK = 256;
constexpr int WAVES = BLOCK / 64;
constexpr float IMG = 640.0f;
constexpr float FG_IOU = 0.7f;
constexpr float BG_IOU = 0.3f;
constexpr int GRID1D = 64;                 // 64x64 cells of 10px
constexpr int NBIN = GRID1D * GRID1D;
// key(iou=0, anchor=0): correct answer for an all-zero column (numpy argmax=0)
constexpr unsigned long long KEY_INIT = 0xFFFFFFFFull;

// ---- d_ws layout (bytes) ----
constexpr size_t OFF_COUNTER = 0;                              // 1 u32
constexpr size_t OFF_KEYS    = 256;                            // B*G u64
constexpr size_t OFF_BINS    = OFF_KEYS + (size_t)B * G * 8;   // B*NBIN u32
constexpr size_t OFF_CURS    = OFF_BINS + (size_t)B * NBIN * 4;
constexpr size_t OFF_PERM    = OFF_CURS + (size_t)B * NBIN * 4;

__device__ __forceinline__ int bin_of(float cx, float cy) {
    int bx = (int)(cx * 0.1f); bx = bx < 0 ? 0 : (bx > GRID1D - 1 ? GRID1D - 1 : bx);
    int by = (int)(cy * 0.1f); by = by < 0 ? 0 : (by > GRID1D - 1 ? GRID1D - 1 : by);
    return by * GRID1D + bx;
}

__global__ void init_ws(unsigned* counter, unsigned long long* keys,
                        unsigned* bins, int zero_bins) {
    int i = blockIdx.x * blockDim.x + threadIdx.x;
    if (i == 0) *counter = 0u;
    if (i < B * G) keys[i] = KEY_INIT;
    if (zero_bins) {
        for (int j = i; j < B * NBIN; j += gridDim.x * blockDim.x) bins[j] = 0u;
    }
}

__global__ void hist_kernel(const float4* __restrict__ anchors,
                            unsigned* __restrict__ bins, int A) {
    int i = blockIdx.x * blockDim.x + threadIdx.x;   // anchor within batch
    int b = blockIdx.y;
    if (i >= A) return;
    float4 an = anchors[(size_t)b * A + i];
    atomicAdd(&bins[b * NBIN + bin_of(an.x, an.y)], 1u);
}

__global__ __launch_bounds__(1024) void scan_bins(const unsigned* __restrict__ bins,
                                                  unsigned* __restrict__ cursors) {
    __shared__ unsigned s[1024];
    const int b = blockIdx.x;
    const unsigned* cnt = bins + b * NBIN;
    unsigned* cur = cursors + b * NBIN;
    const int t = threadIdx.x;
    unsigned v0 = cnt[t * 4 + 0], v1 = cnt[t * 4 + 1];
    unsigned v2 = cnt[t * 4 + 2], v3 = cnt[t * 4 + 3];
    unsigned sum = v0 + v1 + v2 + v3;
    s[t] = sum;
    __syncthreads();
    for (int off = 1; off < 1024; off <<= 1) {
        unsigned x = (t >= off) ? s[t - off] : 0u;
        __syncthreads();
        s[t] += x;
        __syncthreads();
    }
    unsigned excl = s[t] - sum;
    cur[t * 4 + 0] = excl;
    cur[t * 4 + 1] = excl + v0;
    cur[t * 4 + 2] = excl + v0 + v1;
    cur[t * 4 + 3] = excl + v0 + v1 + v2;
}

__global__ void scatter_kernel(const float4* __restrict__ anchors,
                               unsigned* __restrict__ cursors,
                               unsigned* __restrict__ perm, int A) {
    int i = blockIdx.x * blockDim.x + threadIdx.x;
    int b = blockIdx.y;
    if (i >= A) return;
    float4 an = anchors[(size_t)b * A + i];
    unsigned slot = atomicAdd(&cursors[b * NBIN + bin_of(an.x, an.y)], 1u);
    perm[(size_t)b * A + slot] = (unsigned)i;
}

__global__ __launch_bounds__(BLOCK) void assign_main(
    const float4* __restrict__ anchors,   // [B*A] cxcywh
    const float4* __restrict__ gt,        // [B*G] xyxy
    float* __restrict__ L,                // labels out [B*A]
    float4* __restrict__ M,               // matched out [B*A]
    float* __restrict__ V,                // max_iou out [B*A]
    unsigned long long* __restrict__ keys,// [B*G] column argmax keys
    const unsigned* __restrict__ perm,
    unsigned* __restrict__ counter,
    int A, int bpb, int use_perm, int nblocks) {
#pragma clang fp contract(off)
    __shared__ float4 sgt[G];
    __shared__ float sarea[G];
    __shared__ unsigned long long swkey[WAVES][G];
    __shared__ int amLast;
    __shared__ int tgtA[G];

    const int b = blockIdx.x / bpb;
    const int t = threadIdx.x;
    const int lane = t & 63;
    const int wid = t >> 6;
    const int pos = (blockIdx.x % bpb) * BLOCK + t;
    const int p = use_perm ? (int)perm[(size_t)b * A + pos] : pos;

    if (t < G) {
        float4 gb = gt[b * G + t];
        sgt[t] = gb;
        sarea[t] = (gb.z - gb.x) * (gb.w - gb.y);
    }
    __syncthreads();
    const float4 gtl = sgt[lane];          // lane 'lane' tests gt 'lane'

    const size_t idx = (size_t)b * A + p;
    float4 an = anchors[idx];
    float ax0 = an.x - 0.5f * an.z;
    float ay0 = an.y - 0.5f * an.w;
    float ax1 = an.x + 0.5f * an.z;
    float ay1 = an.y + 0.5f * an.w;
    float area_a = (ax1 - ax0) * (ay1 - ay0);

    // wave bounding box of anchor boxes
    float wbx0 = ax0, wby0 = ay0, wbx1 = ax1, wby1 = ay1;
#pragma unroll
    for (int m = 1; m < 64; m <<= 1) {
        wbx0 = fminf(wbx0, __shfl_xor(wbx0, m));
        wby0 = fminf(wby0, __shfl_xor(wby0, m));
        wbx1 = fmaxf(wbx1, __shfl_xor(wbx1, m));
        wby1 = fmaxf(wby1, __shfl_xor(wby1, m));
    }
    // conservative: gt can overlap some lane only if it overlaps the wave bbox
    bool hit = (wbx1 > gtl.x) && (wbx0 < gtl.z) && (wby1 > gtl.y) && (wby0 < gtl.w);
    unsigned long long mask = __ballot(hit);

    float maxv = 0.0f;                     // all-skipped row => max_iou 0, argmax 0
    int maxg = 0;
    unsigned long long acc = 0ull;
    const unsigned inv_p = 0xFFFFFFFFu - (unsigned)p;

    while (mask) {
        const int g = __ffsll(mask) - 1;
        mask &= mask - 1;
        float4 gb = sgt[g];
        float sa = sarea[g];
        float lx = fmaxf(ax0, gb.x);
        float ly = fmaxf(ay0, gb.y);
        float rx = fminf(ax1, gb.z);
        float ry = fminf(ay1, gb.w);
        float w = fmaxf(rx - lx, 0.0f);
        float h = fmaxf(ry - ly, 0.0f);
        float inter = w * h;
        float uni = area_a + sa - inter;
        float iou = inter / uni;           // IEEE div: bit-exact vs numpy

        // row argmax (g visited in increasing order -> strict > keeps first max)
        bool better = iou > maxv;
        maxv = better ? iou : maxv;
        maxg = better ? g : maxg;

        // column argmax: wave max + lowest-lane winner, key carries orig index
        float wm = iou;
#pragma unroll
        for (int m = 1; m < 64; m <<= 1) wm = fmaxf(wm, __shfl_xor(wm, m));
        if (wm > 0.0f) {
            unsigned long long bal = __ballot(iou == wm);
            int wl = __ffsll(bal) - 1;
            unsigned inv_win = __shfl(inv_p, wl);
            unsigned long long key =
                ((unsigned long long)__float_as_uint(wm) << 32) | inv_win;
            if (lane == g && key > acc) acc = key;
        }
    }

    bool fg = maxv > FG_IOU;
    bool bg = maxv < BG_IOU;
    bool cross = (ax0 < 0.0f) || (ay0 < 0.0f) || (ax1 > IMG) || (ay1 > IMG);

    L[idx] = cross ? -1.0f : (fg ? 1.0f : (bg ? 0.0f : -1.0f));
    M[idx] = fg ? sgt[maxg] : make_float4(0.0f, 0.0f, 0.0f, 0.0f);
    V[idx] = maxv;

    // block-level column reduce, then one global atomic per column
    swkey[wid][lane] = acc;
    __syncthreads();
    if (t < G) {
        unsigned long long k = swkey[0][t];
        for (int w = 1; w < WAVES; ++w) k = (swkey[w][t] > k) ? swkey[w][t] : k;
        if (k) atomicMax(&keys[b * G + t], k);
    }

    // ---- inline rule-1 fixup in the last finishing block ----
    __threadfence();
    __syncthreads();
    if (t == 0) {
        unsigned prev = atomicAdd(counter, 1u);
        amLast = (prev == (unsigned)(nblocks - 1)) ? 1 : 0;
    }
    __syncthreads();
    if (amLast) {
        __threadfence();
        for (int bb = 0; bb < B; ++bb) {
            unsigned a = 0u;
            if (t < G) {
                unsigned long long key = __hip_atomic_load(
                    &keys[bb * G + t], __ATOMIC_RELAXED, __HIP_MEMORY_SCOPE_AGENT);
                a = 0xFFFFFFFFu - (unsigned)(key & 0xFFFFFFFFull);
                tgtA[t] = (int)a;
            }
            __syncthreads();
            if (t < G) {
                // numpy scatter is last-write-wins: write iff no later g' hits same anchor
                bool write = true;
                for (int g2 = t + 1; g2 < G; ++g2)
                    if (tgtA[g2] == (int)a) { write = false; break; }
                if (write) {
                    size_t idx2 = (size_t)bb * A + a;
                    float4 an2 = anchors[idx2];
                    float bx0 = an2.x - 0.5f * an2.z;
                    float by0 = an2.y - 0.5f * an2.w;
                    float bx1 = an2.x + 0.5f * an2.z;
                    float by1 = an2.y + 0.5f * an2.w;
                    bool cr = (bx0 < 0.0f) || (by0 < 0.0f) || (bx1 > IMG) || (by1 > IMG);
                    L[idx2] = cr ? -1.0f : 1.0f;   // rule1 overrides bg; cross wins
                    float v = __hip_atomic_load(&V[idx2], __ATOMIC_RELAXED,
                                                __HIP_MEMORY_SCOPE_AGENT);
                    if (!(v > FG_IOU)) M[idx2] = gt[bb * G + t];  // fg keeps rule-2 box
                }
            }
            __syncthreads();
        }
    }
}

extern "C" void kernel_launch(void* const* d_in, const int* in_sizes, int n_in,
                              void* d_out, int out_size, void* d_ws, size_t ws_size,
                              hipStream_t stream) {
    const float4* anchors = (const float4*)d_in[0];
    const float4* gt      = (const float4*)d_in[1];
    const int A = in_sizes[0] / (B * 4);

    float* out = (float*)d_out;
    float*  L = out;
    float4* M = (float4*)(out + (size_t)B * A);
    float*  V = out + (size_t)B * A * 5;

    char* ws = (char*)d_ws;
    unsigned* counter          = (unsigned*)(ws + OFF_COUNTER);
    unsigned long long* keys   = (unsigned long long*)(ws + OFF_KEYS);
    unsigned* bins             = (unsigned*)(ws + OFF_BINS);
    unsigned* cursors          = (unsigned*)(ws + OFF_CURS);
    unsigned* perm             = (unsigned*)(ws + OFF_PERM);

    const size_t ws_need = OFF_PERM + (size_t)B * A * 4;
    const int use_perm = (ws_size >= ws_need) ? 1 : 0;

    init_ws<<<128, 256, 0, stream>>>(counter, keys, bins, use_perm);

    const int bpb = (A + BLOCK - 1) / BLOCK;
    if (use_perm) {
        dim3 g2(bpb, B);
        hist_kernel<<<g2, BLOCK, 0, stream>>>(anchors, bins, A);
        scan_bins<<<B, 1024, 0, stream>>>(bins, cursors);
        scatter_kernel<<<g2, BLOCK, 0, stream>>>(anchors, cursors, perm, A);
    }
    const int nblocks = B * bpb;
    assign_main<<<nblocks, BLOCK, 0, stream>>>(anchors, gt, L, M, V, keys,
                                               perm, counter, A, bpb, use_perm, nblocks);
}

// Round 5
// 142.429 us; speedup vs baseline: 8.0155x; 8.0155x over previous
//
#include <hip/hip_runtime.h>

// RPN anchor-target assignment. B=8, A=184320, G=64.
// Outputs (flat float32, concatenated): labels[B*A], matched[B*A*4], max_iou[B*A].
// Requires A % 256 == 0 (184320 = 720*256).
//
// Sparse-mask strategy (NO permutation — all global access coalesced):
// per block, build 4 quantized interval tables (u64[64]) over the 64 gts;
// each anchor gets a conservative superset mask of possibly-overlapping gts
// (4 LDS lookups + 3 ands), then runs the exact IEEE IoU loop only over mask
// bits (~12 avg). Skipped pairs have true iou==0, handled exactly by
// maxv init 0 / KEY_INIT. Column argmax via sparse LDS u64 atomicMax.

constexpr int B = 8;
constexpr int G = 64;
constexpr int BLOCK = 256;
constexpr float IMG = 640.0f;
constexpr float FG_IOU = 0.7f;
constexpr float BG_IOU = 0.3f;
constexpr float SLACK = 1.0f;   // widen quantized thresholds: kills fp-rounding edge cases
// key(iou=0, anchor=0): correct for an all-zero column (numpy argmax = 0).
// Computed-zero keys (0, inv_a) with a>0 are < KEY_INIT, so they never displace it.
constexpr unsigned long long KEY_INIT = 0xFFFFFFFFull;

__global__ __launch_bounds__(BLOCK) void assign_main(
    const float4* __restrict__ anchors,   // [B*A] cxcywh
    const float4* __restrict__ gt,        // [B*G] xyxy
    float* __restrict__ L,                // labels out [B*A]
    float4* __restrict__ M,               // matched out [B*A]
    float* __restrict__ V,                // max_iou out [B*A]
    long long* __restrict__ gkeys,        // [B*G] global argmax keys (signed max;
                                          //  d_ws 0xAA poison is negative == -inf)
    int A, int bpb) {
#pragma clang fp contract(off)
    __shared__ float4 sgt[G];
    __shared__ unsigned long long tab[4][G];  // 0:xlo 1:xhi 2:ylo 3:yhi
    __shared__ unsigned long long skey[G];

    const int b = blockIdx.x / bpb;
    const int t = threadIdx.x;
    const int lane = t & 63;
    const int wv = t >> 6;
    const int a = (blockIdx.x % bpb) * BLOCK + t;

    if (t < G) {
        sgt[t] = gt[b * G + t];
        skey[t] = KEY_INIT;
    }
    __syncthreads();

    // ---- build interval tables; wave wv builds table wv (wave-uniform comp/sense)
    // table 0 (xlo): gt.x0 < (s+1)*10 + SLACK   (superset of gx0 < ax1, s=strip(ax1))
    // table 1 (xhi): gt.x1 > s*10 - SLACK       (superset of gx1 > ax0, s=strip(ax0))
    // table 2 (ylo): gt.y0 < (s+1)*10 + SLACK
    // table 3 (yhi): gt.y1 > s*10 - SLACK
    {
        const int comp = (wv == 0) ? 0 : (wv == 1) ? 2 : (wv == 2) ? 1 : 3;
        const bool hi = (wv & 1) != 0;
        const float thr = hi ? (lane * 10.0f - SLACK)
                             : ((lane + 1) * 10.0f + SLACK);
        unsigned long long m = 0ull;
        for (int g = 0; g < G; ++g) {
            float c = ((const float*)&sgt[g])[comp];   // wave-uniform address
            bool in = hi ? (c > thr) : (c < thr);
            if (in) m |= (1ull << g);
        }
        tab[wv][lane] = m;
    }
    __syncthreads();

    const size_t idx = (size_t)b * A + a;
    float4 an = anchors[idx];
    float ax0 = an.x - 0.5f * an.z;
    float ay0 = an.y - 0.5f * an.w;
    float ax1 = an.x + 0.5f * an.z;
    float ay1 = an.y + 0.5f * an.w;
    float area_a = (ax1 - ax0) * (ay1 - ay0);

    // strips (trunc-toward-zero + clamp == clamped floor for our ranges)
    int sx0 = (int)(ax0 * 0.1f); sx0 = sx0 < 0 ? 0 : (sx0 > 63 ? 63 : sx0);
    int sx1 = (int)(ax1 * 0.1f); sx1 = sx1 < 0 ? 0 : (sx1 > 63 ? 63 : sx1);
    int sy0 = (int)(ay0 * 0.1f); sy0 = sy0 < 0 ? 0 : (sy0 > 63 ? 63 : sy0);
    int sy1 = (int)(ay1 * 0.1f); sy1 = sy1 < 0 ? 0 : (sy1 > 63 ? 63 : sy1);

    unsigned long long mask = tab[0][sx1] & tab[1][sx0] & tab[2][sy1] & tab[3][sy0];

    float maxv = 0.0f;   // all-masked-out row => max_iou 0, argmax 0 (numpy exact)
    int maxg = 0;
    const unsigned long long inv_p = (unsigned long long)(0xFFFFFFFFu - (unsigned)a);

    while (mask) {
        const int g = __ffsll(mask) - 1;   // ascending g => strict > keeps first max
        mask &= mask - 1;
        float4 gb = sgt[g];
        float sa = (gb.z - gb.x) * (gb.w - gb.y);
        float lx = fmaxf(ax0, gb.x);
        float ly = fmaxf(ay0, gb.y);
        float rx = fminf(ax1, gb.z);
        float ry = fminf(ay1, gb.w);
        float w = fmaxf(rx - lx, 0.0f);
        float h = fmaxf(ry - ly, 0.0f);
        float inter = w * h;
        float uni = area_a + sa - inter;
        float iou = inter / uni;           // IEEE div: bit-exact vs numpy

        bool better = iou > maxv;
        maxv = better ? iou : maxv;
        maxg = better ? g : maxg;

        unsigned long long key =
            ((unsigned long long)__float_as_uint(iou) << 32) | inv_p;
        atomicMax(&skey[g], key);          // sparse: low contention
    }

    bool fg = maxv > FG_IOU;
    bool bg = maxv < BG_IOU;
    bool cross = (ax0 < 0.0f) || (ay0 < 0.0f) || (ax1 > IMG) || (ay1 > IMG);

    L[idx] = cross ? -1.0f : (fg ? 1.0f : (bg ? 0.0f : -1.0f));
    M[idx] = fg ? sgt[maxg] : make_float4(0.0f, 0.0f, 0.0f, 0.0f);
    V[idx] = maxv;

    __syncthreads();
    if (t < G) {
        // unconditional: every column must receive >= KEY_INIT (gkeys is poisoned)
        atomicMax(&gkeys[b * G + t], (long long)skey[t]);
    }
}

// Rule 1 fixup: one block per batch, thread per gt. numpy scatter is
// last-write-wins; thread g writes only if no later g' targets the same anchor.
__global__ void fixup(
    const float4* __restrict__ anchors,
    const float4* __restrict__ gt,
    const long long* __restrict__ gkeys,
    float* __restrict__ L,
    float4* __restrict__ M,
    const float* __restrict__ V,
    int A) {
#pragma clang fp contract(off)
    const int b = blockIdx.x;
    const int g = threadIdx.x;
    __shared__ int tgt[G];

    unsigned long long key = (unsigned long long)gkeys[b * G + g];
    unsigned int a = 0xFFFFFFFFu - (unsigned int)(key & 0xFFFFFFFFull);
    tgt[g] = (int)a;
    __syncthreads();

    bool write = true;
    for (int g2 = g + 1; g2 < G; ++g2)
        if (tgt[g2] == (int)a) { write = false; break; }
    if (!write) return;

    const size_t idx = (size_t)b * A + a;
    float4 an = anchors[idx];
    float ax0 = an.x - 0.5f * an.z;
    float ay0 = an.y - 0.5f * an.w;
    float ax1 = an.x + 0.5f * an.z;
    float ay1 = an.y + 0.5f * an.w;
    bool cross = (ax0 < 0.0f) || (ay0 < 0.0f) || (ax1 > IMG) || (ay1 > IMG);
    // Rule 1 label=1 overrides rule-3 bg; cross filter still wins.
    L[idx] = cross ? -1.0f : 1.0f;
    // Rule 2 (fg) overrides rule 1's matched box; otherwise rule 1 assigns gt[g].
    if (!(V[idx] > FG_IOU)) M[idx] = gt[b * G + g];
}

extern "C" void kernel_launch(void* const* d_in, const int* in_sizes, int n_in,
                              void* d_out, int out_size, void* d_ws, size_t ws_size,
                              hipStream_t stream) {
    const float4* anchors = (const float4*)d_in[0];
    const float4* gt      = (const float4*)d_in[1];
    const int A = in_sizes[0] / (B * 4);

    float* out = (float*)d_out;
    float*  L = out;                                 // [B*A]
    float4* M = (float4*)(out + (size_t)B * A);      // [B*A] float4
    float*  V = out + (size_t)B * A * 5;             // [B*A]
    long long* gkeys = (long long*)d_ws;             // [B*G], poison 0xAA == -inf

    const int bpb = (A + BLOCK - 1) / BLOCK;
    assign_main<<<B * bpb, BLOCK, 0, stream>>>(anchors, gt, L, M, V, gkeys, A, bpb);
    fixup<<<B, G, 0, stream>>>(anchors, gt, gkeys, L, M, V, A);
}